// Round 1
// baseline (240.855 us; speedup 1.0000x reference)
//
#include <hip/hip_runtime.h>

// Problem constants (B, C=1, H, W) from the reference.
#define H_ 1024
#define W_ 1024
#define B_ 16
#define ROWS 8                 // output rows per block
#define GX (H_ / ROWS)         // 128 blocks in y-dim of image
#define NBLK (GX * B_)         // 2048 total blocks -> 2048*13 float partials in d_ws

// partial layout per block: [0]=sum_pred,
// then for k=3,5,7: {sum_dil, sum_pred*dil, sum_ero, sum_pred*ero}
#define NACC 13

template<bool M>
__device__ __forceinline__ float O(float a, float b) { return M ? fmaxf(a, b) : fminf(a, b); }

// a[0..11] covers columns x0-4 .. x0+7; outputs are columns x0..x0+3 (a-index 4..7).
// w1[c] = op over a[c+3..c+5]   (window 3 centered at a-index c+4)
// w2[c] = op over a[c+2..c+6]   (window 5)
// w3[c] = op over a[c+1..c+7]   (window 7)
// Unused outputs are dead-code-eliminated after inlining.
template<bool M>
__device__ __forceinline__ void windows(const float a[12], float w1[4], float w2[4], float w3[4]) {
  float P[12], Q[12];
#pragma unroll
  for (int i = 1; i <= 8; i++) P[i] = O<M>(a[i], a[i + 1]);       // op over a[i..i+1]
#pragma unroll
  for (int i = 1; i <= 7; i++) Q[i] = O<M>(P[i], a[i + 2]);       // op over a[i..i+2]
#pragma unroll
  for (int c = 4; c < 8; c++) {
    w1[c - 4] = Q[c - 1];
    w2[c - 4] = O<M>(Q[c - 2], P[c + 1]);
    w3[c - 4] = O<M>(O<M>(Q[c - 3], Q[c]), a[c + 3]);
  }
}

__global__ __launch_bounds__(256) void k_partials(const float* __restrict__ pred,
                                                  const float* __restrict__ tch,
                                                  float* __restrict__ partials) {
  const int tid = threadIdx.x;
  const int b   = blockIdx.y;
  const int y0  = blockIdx.x * ROWS;
  const int x0  = tid * 4;

  float acc[NACC];
#pragma unroll
  for (int j = 0; j < NACC; j++) acc[j] = 0.f;

  for (int r = 0; r < ROWS; r++) {
    const int y = y0 + r;
    const float4 pv = *reinterpret_cast<const float4*>(pred + ((size_t)b * H_ + y) * W_ + x0);

    float dil3[4], dil5[4], dil7[4], ero3[4], ero5[4], ero7[4];
#pragma unroll
    for (int c = 0; c < 4; c++) {
      dil3[c] = dil5[c] = dil7[c] = -1.0e4f;
      ero3[c] = ero5[c] = ero7[c] =  1.0e4f;
    }

#pragma unroll
    for (int dy = -3; dy <= 3; ++dy) {
      const int row = y + dy;
      float aM[12], aN[12];
#pragma unroll
      for (int i = 0; i < 12; i++) { aM[i] = -1.0e4f; aN[i] = 1.0e4f; }
      if ((unsigned)row < (unsigned)H_) {
        const float* tr = tch + ((size_t)b * H_ + row) * W_;
        {
          float4 v = *reinterpret_cast<const float4*>(tr + x0);
          aM[4] = aN[4] = v.x; aM[5] = aN[5] = v.y; aM[6] = aN[6] = v.z; aM[7] = aN[7] = v.w;
        }
        if (tid > 0) {
          float4 v = *reinterpret_cast<const float4*>(tr + x0 - 4);
          aM[0] = aN[0] = v.x; aM[1] = aN[1] = v.y; aM[2] = aN[2] = v.z; aM[3] = aN[3] = v.w;
        }
        if (tid < 255) {
          float4 v = *reinterpret_cast<const float4*>(tr + x0 + 4);
          aM[8] = aN[8] = v.x; aM[9] = aN[9] = v.y; aM[10] = aN[10] = v.z; aM[11] = aN[11] = v.w;
        }
      }
      const int ady = dy < 0 ? -dy : dy;   // constant after unroll
      if (ady == 3) {
#pragma unroll
        for (int c = 0; c < 4; c++) {
          dil7[c] = fmaxf(dil7[c], aM[c + 4]);
          ero7[c] = fminf(ero7[c], aN[c + 4]);
        }
      } else if (ady == 2) {
        float w1M[4], w2M[4], w3M[4], w1N[4], w2N[4], w3N[4];
        windows<true>(aM, w1M, w2M, w3M);
        windows<false>(aN, w1N, w2N, w3N);
#pragma unroll
        for (int c = 0; c < 4; c++) {
          dil5[c] = fmaxf(dil5[c], aM[c + 4]);  dil7[c] = fmaxf(dil7[c], w2M[c]);
          ero5[c] = fminf(ero5[c], aN[c + 4]);  ero7[c] = fminf(ero7[c], w2N[c]);
        }
      } else if (ady == 1) {
        float w1M[4], w2M[4], w3M[4], w1N[4], w2N[4], w3N[4];
        windows<true>(aM, w1M, w2M, w3M);
        windows<false>(aN, w1N, w2N, w3N);
#pragma unroll
        for (int c = 0; c < 4; c++) {
          dil3[c] = fmaxf(dil3[c], aM[c + 4]);
          dil5[c] = fmaxf(dil5[c], w1M[c]);
          dil7[c] = fmaxf(dil7[c], w2M[c]);
          ero3[c] = fminf(ero3[c], aN[c + 4]);
          ero5[c] = fminf(ero5[c], w1N[c]);
          ero7[c] = fminf(ero7[c], w2N[c]);
        }
      } else {  // dy == 0
        float w1M[4], w2M[4], w3M[4], w1N[4], w2N[4], w3N[4];
        windows<true>(aM, w1M, w2M, w3M);
        windows<false>(aN, w1N, w2N, w3N);
#pragma unroll
        for (int c = 0; c < 4; c++) {
          dil3[c] = fmaxf(dil3[c], w1M[c]);
          dil5[c] = fmaxf(dil5[c], w2M[c]);
          dil7[c] = fmaxf(dil7[c], w3M[c]);
          ero3[c] = fminf(ero3[c], w1N[c]);
          ero5[c] = fminf(ero5[c], w2N[c]);
          ero7[c] = fminf(ero7[c], w3N[c]);
        }
      }
    }

#pragma unroll
    for (int c = 0; c < 4; c++) {
      const float p = (c == 0) ? pv.x : (c == 1) ? pv.y : (c == 2) ? pv.z : pv.w;
      acc[0]  += p;
      acc[1]  += dil3[c];  acc[2]  += p * dil3[c];
      acc[3]  += ero3[c];  acc[4]  += p * ero3[c];
      acc[5]  += dil5[c];  acc[6]  += p * dil5[c];
      acc[7]  += ero5[c];  acc[8]  += p * ero5[c];
      acc[9]  += dil7[c];  acc[10] += p * dil7[c];
      acc[11] += ero7[c];  acc[12] += p * ero7[c];
    }
  }

  // wave (64-lane) shuffle reduction, then cross-wave via LDS
#pragma unroll
  for (int j = 0; j < NACC; j++) {
    float v = acc[j];
#pragma unroll
    for (int off = 32; off > 0; off >>= 1) v += __shfl_down(v, off, 64);
    acc[j] = v;
  }
  __shared__ float red[4][NACC];
  const int lane = tid & 63, wv = tid >> 6;
  if (lane == 0) {
#pragma unroll
    for (int j = 0; j < NACC; j++) red[wv][j] = acc[j];
  }
  __syncthreads();
  if (tid == 0) {
    const int bid = blockIdx.y * gridDim.x + blockIdx.x;
#pragma unroll
    for (int j = 0; j < NACC; j++)
      partials[bid * NACC + j] = red[0][j] + red[1][j] + red[2][j] + red[3][j];
  }
}

__global__ __launch_bounds__(256) void k_final(const float* __restrict__ partials,
                                               float* __restrict__ out) {
  double acc[NACC];
#pragma unroll
  for (int j = 0; j < NACC; j++) acc[j] = 0.0;
  for (int i = threadIdx.x; i < NBLK; i += 256) {
#pragma unroll
    for (int j = 0; j < NACC; j++) acc[j] += (double)partials[i * NACC + j];
  }
  __shared__ double red[NACC][256];
#pragma unroll
  for (int j = 0; j < NACC; j++) red[j][threadIdx.x] = acc[j];
  __syncthreads();
  for (int s = 128; s > 0; s >>= 1) {
    if (threadIdx.x < (unsigned)s) {
#pragma unroll
      for (int j = 0; j < NACC; j++) red[j][threadIdx.x] += red[j][threadIdx.x + s];
    }
    __syncthreads();
  }
  if (threadIdx.x == 0) {
    const double Sp = red[0][0];
    double total = 0.0;
#pragma unroll
    for (int k = 0; k < 3; k++) {
      const double Sd = red[1 + 4 * k][0], Id = red[2 + 4 * k][0];
      const double Se = red[3 + 4 * k][0], Ie = red[4 + 4 * k][0];
      double cd = Sp + Sd; if (cd < 1e-7) cd = 1e-7;
      double ce = Sp + Se; if (ce < 1e-7) ce = 1e-7;
      total += (1.0 - 2.0 * Id / cd) * (Sd > 0.0 ? 1.0 : 0.0);
      total += (1.0 - 2.0 * Ie / ce) * (Se > 0.0 ? 1.0 : 0.0);
    }
    out[0] = (float)(total / 3.0);
  }
}

extern "C" void kernel_launch(void* const* d_in, const int* in_sizes, int n_in,
                              void* d_out, int out_size, void* d_ws, size_t ws_size,
                              hipStream_t stream) {
  const float* pred = (const float*)d_in[0];  // pred_student_prob
  const float* tch  = (const float*)d_in[1];  // teacher_prob
  float* partials = (float*)d_ws;             // NBLK * NACC floats; fully written each launch

  k_partials<<<dim3(GX, B_), 256, 0, stream>>>(pred, tch, partials);
  k_final<<<1, 256, 0, stream>>>(partials, (float*)d_out);
}

// Round 2
// 164.677 us; speedup vs baseline: 1.4626x; 1.4626x over previous
//
#include <hip/hip_runtime.h>

// Problem constants (B, C=1, H, W) from the reference.
#define H_ 1024
#define W_ 1024
#define B_ 16
#define TH 8                   // output rows per block
#define STEPS (TH + 6)         // input rows streamed (halo 3 each side)
#define GX (H_ / TH)           // 128 blocks in y-dim of image
#define NBLK (GX * B_)         // 2048 blocks -> 2048*13 float partials in d_ws
#define NACC 13

// Sliding-row gather stencil.
// Per input row t we build horizontal windows once:
//   h0 = raw, h3 = 3-wide, h5 = 5-wide, h7 = 7-wide (max for dilation, min for erosion)
// and push them into register ring-queues. Output row y (= t-3) is emitted via
//   k3 = op(h3[y], h0[y-1], h0[y+1])
//   k5 = op(h5[y], h3[y-1], h3[y+1], h0[y-2], h0[y+2])
//   k7 = op(h7[y], h5[y-1], h5[y+1], h5[y-2], h5[y+2], h0[y-3], h0[y+3])
// which matches the elliptical supports exactly.
// Boundary handling: geodesic (exclude-OOB) morphology equals clamped-index
// morphology here, because a clamped tap duplicates a value that lies inside a
// wider (superset) part of the window -> harmless for both max and min.

__global__ __launch_bounds__(256, 2) void k_partials(const float* __restrict__ pred,
                                                     const float* __restrict__ tch,
                                                     float* __restrict__ partials) {
  const int tid = threadIdx.x;
  const int b   = blockIdx.y;
  const int y0  = blockIdx.x * TH;
  const int x0  = tid * 4;
  const float* tb = tch  + (size_t)b * (H_ * W_);
  const float* pb = pred + (size_t)b * (H_ * W_);

  float acc[NACC];
#pragma unroll
  for (int j = 0; j < NACC; j++) acc[j] = 0.f;

  // register ring queues (indices constant-fold after full unroll)
  float h0q[7][4];
  float h3M[5][4], h3N[5][4];
  float h5M[6][4], h5N[6][4];
  float h7M[4][4], h7N[4][4];

#pragma unroll
  for (int s = 0; s < STEPS; ++s) {
    const int t    = y0 + s - 3;
    const int trow = t < 0 ? 0 : (t >= H_ ? H_ - 1 : t);   // exact (subset argument)
    const float* tr = tb + (size_t)trow * W_;

    // a[0..11] = columns x0-4 .. x0+7, x-clamped at image edges (exact).
    float a[12];
    const float4 cv = *reinterpret_cast<const float4*>(tr + x0);
    a[4] = cv.x; a[5] = cv.y; a[6] = cv.z; a[7] = cv.w;
    if (tid > 0) {
      const float4 lv = *reinterpret_cast<const float4*>(tr + x0 - 4);
      a[0] = lv.x; a[1] = lv.y; a[2] = lv.z; a[3] = lv.w;
    } else {
      a[0] = a[1] = a[2] = a[3] = cv.x;
    }
    if (tid < 255) {
      const float4 rv = *reinterpret_cast<const float4*>(tr + x0 + 4);
      a[8] = rv.x; a[9] = rv.y; a[10] = rv.z; a[11] = rv.w;
    } else {
      a[8] = a[9] = a[10] = a[11] = cv.w;
    }

    // 3-wide sliding windows Q[i] over a[i..i+2] (v_max3 / v_min3)
    float QM[8], QN[8];
#pragma unroll
    for (int i = 1; i <= 7; ++i) {
      QM[i] = fmaxf(fmaxf(a[i], a[i + 1]), a[i + 2]);
      QN[i] = fminf(fminf(a[i], a[i + 1]), a[i + 2]);
    }
    // push this row's windows
#pragma unroll
    for (int c = 0; c < 4; ++c) {
      h0q[s % 7][c] = a[c + 4];
      h3M[s % 5][c] = QM[c + 3];
      h3N[s % 5][c] = QN[c + 3];
      h5M[s % 6][c] = fmaxf(QM[c + 2], QM[c + 4]);
      h5N[s % 6][c] = fminf(QN[c + 2], QN[c + 4]);
      h7M[s % 4][c] = fmaxf(fmaxf(QM[c + 1], QM[c + 4]), a[c + 7]);
      h7N[s % 4][c] = fminf(fminf(QN[c + 1], QN[c + 4]), a[c + 7]);
    }

    // emit output row y = t-3  (row y+d was pushed at step s-3+d)
    if (s >= 6) {
      const int j = s - 6;
      const float4 pv = *reinterpret_cast<const float4*>(pb + (size_t)(y0 + j) * W_ + x0);
      const float p[4] = {pv.x, pv.y, pv.z, pv.w};
#pragma unroll
      for (int c = 0; c < 4; ++c) {
        const float d3v = fmaxf(fmaxf(h3M[(s + 2) % 5][c], h0q[(s + 3) % 7][c]), h0q[(s + 5) % 7][c]);
        const float e3v = fminf(fminf(h3N[(s + 2) % 5][c], h0q[(s + 3) % 7][c]), h0q[(s + 5) % 7][c]);

        float d5v = fmaxf(fmaxf(h5M[(s + 3) % 6][c], h3M[(s + 1) % 5][c]), h3M[(s + 3) % 5][c]);
        d5v = fmaxf(fmaxf(d5v, h0q[(s + 2) % 7][c]), h0q[(s + 6) % 7][c]);
        float e5v = fminf(fminf(h5N[(s + 3) % 6][c], h3N[(s + 1) % 5][c]), h3N[(s + 3) % 5][c]);
        e5v = fminf(fminf(e5v, h0q[(s + 2) % 7][c]), h0q[(s + 6) % 7][c]);

        float d7v = fmaxf(fmaxf(h7M[(s + 1) % 4][c], h5M[(s + 2) % 6][c]), h5M[(s + 4) % 6][c]);
        d7v = fmaxf(fmaxf(d7v, h5M[(s + 1) % 6][c]), h5M[(s + 5) % 6][c]);
        d7v = fmaxf(fmaxf(d7v, h0q[(s + 1) % 7][c]), h0q[s % 7][c]);
        float e7v = fminf(fminf(h7N[(s + 1) % 4][c], h5N[(s + 2) % 6][c]), h5N[(s + 4) % 6][c]);
        e7v = fminf(fminf(e7v, h5N[(s + 1) % 6][c]), h5N[(s + 5) % 6][c]);
        e7v = fminf(fminf(e7v, h0q[(s + 1) % 7][c]), h0q[s % 7][c]);

        acc[0]  += p[c];
        acc[1]  += d3v;  acc[2]  = fmaf(p[c], d3v, acc[2]);
        acc[3]  += e3v;  acc[4]  = fmaf(p[c], e3v, acc[4]);
        acc[5]  += d5v;  acc[6]  = fmaf(p[c], d5v, acc[6]);
        acc[7]  += e5v;  acc[8]  = fmaf(p[c], e5v, acc[8]);
        acc[9]  += d7v;  acc[10] = fmaf(p[c], d7v, acc[10]);
        acc[11] += e7v;  acc[12] = fmaf(p[c], e7v, acc[12]);
      }
    }
  }

  // wave (64-lane) shuffle reduction, then cross-wave via LDS
#pragma unroll
  for (int j = 0; j < NACC; j++) {
    float v = acc[j];
#pragma unroll
    for (int off = 32; off > 0; off >>= 1) v += __shfl_down(v, off, 64);
    acc[j] = v;
  }
  __shared__ float red[4][NACC];
  const int lane = tid & 63, wv = tid >> 6;
  if (lane == 0) {
#pragma unroll
    for (int j = 0; j < NACC; j++) red[wv][j] = acc[j];
  }
  __syncthreads();
  if (tid == 0) {
    const int bid = blockIdx.y * gridDim.x + blockIdx.x;
#pragma unroll
    for (int j = 0; j < NACC; j++)
      partials[bid * NACC + j] = red[0][j] + red[1][j] + red[2][j] + red[3][j];
  }
}

__global__ __launch_bounds__(256) void k_final(const float* __restrict__ partials,
                                               float* __restrict__ out) {
  double acc[NACC];
#pragma unroll
  for (int j = 0; j < NACC; j++) acc[j] = 0.0;
  for (int i = threadIdx.x; i < NBLK; i += 256) {
#pragma unroll
    for (int j = 0; j < NACC; j++) acc[j] += (double)partials[i * NACC + j];
  }
  __shared__ double red[NACC][256];
#pragma unroll
  for (int j = 0; j < NACC; j++) red[j][threadIdx.x] = acc[j];
  __syncthreads();
  for (int s = 128; s > 0; s >>= 1) {
    if (threadIdx.x < (unsigned)s) {
#pragma unroll
      for (int j = 0; j < NACC; j++) red[j][threadIdx.x] += red[j][threadIdx.x + s];
    }
    __syncthreads();
  }
  if (threadIdx.x == 0) {
    const double Sp = red[0][0];
    double total = 0.0;
#pragma unroll
    for (int k = 0; k < 3; k++) {
      const double Sd = red[1 + 4 * k][0], Id = red[2 + 4 * k][0];
      const double Se = red[3 + 4 * k][0], Ie = red[4 + 4 * k][0];
      double cd = Sp + Sd; if (cd < 1e-7) cd = 1e-7;
      double ce = Sp + Se; if (ce < 1e-7) ce = 1e-7;
      total += (1.0 - 2.0 * Id / cd) * (Sd > 0.0 ? 1.0 : 0.0);
      total += (1.0 - 2.0 * Ie / ce) * (Se > 0.0 ? 1.0 : 0.0);
    }
    out[0] = (float)(total / 3.0);
  }
}

extern "C" void kernel_launch(void* const* d_in, const int* in_sizes, int n_in,
                              void* d_out, int out_size, void* d_ws, size_t ws_size,
                              hipStream_t stream) {
  const float* pred = (const float*)d_in[0];  // pred_student_prob
  const float* tch  = (const float*)d_in[1];  // teacher_prob
  float* partials = (float*)d_ws;             // NBLK * NACC floats; fully written each launch

  k_partials<<<dim3(GX, B_), 256, 0, stream>>>(pred, tch, partials);
  k_final<<<1, 256, 0, stream>>>(partials, (float*)d_out);
}